// Round 11
// baseline (529.352 us; speedup 1.0000x reference)
//
#include <hip/hip_runtime.h>
#include <stdint.h>

typedef unsigned short ushort;
typedef __attribute__((ext_vector_type(8)))  short bfrag;   // 8 bf16 = 4 VGPR
typedef __attribute__((ext_vector_type(16))) float f32x16;  // MFMA 32x32 acc

#define D      64
#define K      1024
#define HW     1024
#define NROWS  65536
#define NELEM  (NROWS * 64)
#define BAND   0.01f

// Output layout (floats, reference return order)
#define O_ZQ   0
#define O_LOSS 4194304
#define O_IDX  4194305
#define O_NCS  4259841
#define O_EMAW 4260865
#define O_EMB  4326401

// Workspace layout (bytes)
#define WB_EH     0x00000   // 1024x64 u16
#define WB_EL     0x20000
#define WB_ESQ    0x40000   // 1024 f32
#define WB_COUNTS 0x43000   // 4KB (zeroed by prep_e)
#define WB_CURSOR 0x44000   // 4KB (zeroed by prep_e)
#define WB_LOSSN  0x45000   // lossa @+0; rcnt @+0x100 (own line) (zeroed)
#define WB_RLIST  0x46000   // 65536 i32 -> 0x86000
#define WB_T1     0x86000   // 2x65536 f32 -> 0x106000
#define WB_T2     0x106000  // 2x65536 f32 -> 0x186000
#define WB_C      0x186000  // 2x65536 i32 -> 0x206000
#define WS_NEED_SPLIT 0x206000
#define WB_ZF     0x300000  // 16 MB sorted rows
#define WS_NEED_FUSED (0x300000 + 0x1000000)

__device__ __forceinline__ unsigned bf16r(float x) {   // RNE f32->bf16 bits
    unsigned u = __float_as_uint(x);
    return (u + 0x7FFFu + ((u >> 16) & 1u)) >> 16;
}
__device__ __forceinline__ float bf16f(unsigned h) {
    return __uint_as_float(h << 16);
}

// ---------------------------------------------------------------------------
// Kernel 0: wave-per-code esq + bf16 hi/lo split; block 0 zeroes control.
// grid 256 x 256.
// ---------------------------------------------------------------------------
__global__ __launch_bounds__(256) void vq_prep_e(
    const float* __restrict__ emb, ushort* __restrict__ eh,
    ushort* __restrict__ el, float* __restrict__ esq,
    unsigned* __restrict__ zero_region)
{
    const int tid = threadIdx.x;
    if (blockIdx.x == 0) {
#pragma unroll
        for (int i = 0; i < 12; ++i) zero_region[i * 256 + tid] = 0u;  // 12 KB
    }
    const int k = blockIdx.x * 4 + (tid >> 6);
    const int d = tid & 63;
    float v = emb[k * 64 + d];
    unsigned hh = bf16r(v);
    float rem = v - bf16f(hh);
    eh[k * 64 + d] = (ushort)hh;
    el[k * 64 + d] = (ushort)bf16r(rem);
    float a = v * v;
#pragma unroll
    for (int off = 32; off; off >>= 1) a += __shfl_xor(a, off);
    if (d == 0) esq[k] = a;
}

// ---------------------------------------------------------------------------
// Kernel 1a: SPLIT-K MFMA dist. grid 1024 = (512 row-tiles x 2 K-splits).
// 34KB LDS -> 4 blocks/CU (4 waves/SIMD). A-frags loaded direct from global.
// Writes per-split (t1,t2,c) to workspace; no atomics.
// ---------------------------------------------------------------------------
__global__ __launch_bounds__(256, 4) void vq_dist_split(
    const float* __restrict__ z, const short* __restrict__ eh_g,
    const short* __restrict__ el_g, const float* __restrict__ esq_g,
    float* __restrict__ ws_t1, float* __restrict__ ws_t2,
    int* __restrict__ ws_c)
{
    __shared__ __align__(16) short eh_lds[2][64 * 64];    // 16 KB
    __shared__ __align__(16) short el_lds[2][64 * 64];    // 16 KB
    __shared__ float esq_lds[512];                        // 2 KB

    const int tid  = threadIdx.x;
    const int lane = tid & 63;
    const int wave = tid >> 6;
    const int col  = lane & 31;
    const int h    = lane >> 5;
    const int bx     = blockIdx.x;
    const int split  = bx & 1;
    const int n0     = (bx >> 1) * 128;
    const int b      = n0 >> 10;
    const int hw0    = n0 & 1023;
    const int cbase0 = split * 512;

    // ---- A-frags (scaled -2z) loaded DIRECT from global (coalesced/32-lane)
    const int wrow = wave * 32 + col;
    const float* zrow = z + (size_t)b * 65536 + hw0 + wrow;
    bfrag zhA[4], zlA[4];
#pragma unroll
    for (int j = 0; j < 4; ++j) {
        int kq = j * 2 + h;
#pragma unroll
        for (int m = 0; m < 8; ++m) {
            float t = -2.0f * zrow[(size_t)(kq * 8 + m) * 1024];
            unsigned hh = bf16r(t);
            zhA[j][m] = (short)hh;
            zlA[j][m] = (short)bf16r(t - bf16f(hh));
        }
    }

#pragma unroll
    for (int it = 0; it < 2; ++it)
        esq_lds[it * 256 + tid] = esq_g[cbase0 + it * 256 + tid];

    // ---- e-chunk staging (64 codes/chunk, 8 chunks/split), double-buffered
    bfrag pfh[2], pfl[2];
    auto loadE = [&](int cb) {
#pragma unroll
        for (int q = 0; q < 2; ++q) {
            int u = q * 256 + tid;
            int code = u >> 3, m = u & 7;
            pfh[q] = *(const bfrag*)&eh_g[(size_t)(cb + code) * 64 + m * 8];
            pfl[q] = *(const bfrag*)&el_g[(size_t)(cb + code) * 64 + m * 8];
        }
    };
    auto writeE = [&](int buf) {
#pragma unroll
        for (int q = 0; q < 2; ++q) {
            int u = q * 256 + tid;
            int code = u >> 3, m = u & 7;
            int unit = ((code >> 5) * 4 + (m >> 1)) * 64 +
                       ((((m & 1) << 5) | (code & 31)) ^ (m & 7));
            *(bfrag*)&eh_lds[buf][unit * 8] = pfh[q];
            *(bfrag*)&el_lds[buf][unit * 8] = pfl[q];
        }
    };

    loadE(cbase0);
    writeE(0);
    loadE(cbase0 + 64);
    __syncthreads();

    float t1s[16], t2s[16];
    unsigned t1c[16];
#pragma unroll
    for (int i = 0; i < 16; ++i) { t1s[i] = INFINITY; t2s[i] = INFINITY; t1c[i] = 0; }

    for (int ch = 0; ch < 8; ++ch) {
        const int cb  = cbase0 + ch * 64;
        const int buf = ch & 1;

        bfrag ehB0[4], elB0[4], ehB1[4], elB1[4];
#pragma unroll
        for (int j = 0; j < 4; ++j) {
            int m = j * 2 + h;
            int sw = (((h << 5) | col) ^ (m & 7));
            ehB0[j] = *(const bfrag*)&eh_lds[buf][(j * 64 + sw) * 8];
            elB0[j] = *(const bfrag*)&el_lds[buf][(j * 64 + sw) * 8];
            ehB1[j] = *(const bfrag*)&eh_lds[buf][((4 + j) * 64 + sw) * 8];
            elB1[j] = *(const bfrag*)&el_lds[buf][((4 + j) * 64 + sw) * 8];
        }
        const float esq0 = esq_lds[ch * 64 + col];
        const float esq1 = esq_lds[ch * 64 + 32 + col];
        const unsigned c0 = cb + col;
        const unsigned c1 = cb + 32 + col;

        f32x16 acc0, acc1;
#pragma unroll
        for (int i = 0; i < 16; ++i) { acc0[i] = esq0; acc1[i] = esq1; }

        __builtin_amdgcn_s_setprio(1);
#pragma unroll
        for (int j = 0; j < 4; ++j) {
            acc0 = __builtin_amdgcn_mfma_f32_32x32x16_bf16(zhA[j], ehB0[j], acc0, 0, 0, 0);
            acc1 = __builtin_amdgcn_mfma_f32_32x32x16_bf16(zhA[j], ehB1[j], acc1, 0, 0, 0);
        }
#pragma unroll
        for (int j = 0; j < 4; ++j) {
            acc0 = __builtin_amdgcn_mfma_f32_32x32x16_bf16(zhA[j], elB0[j], acc0, 0, 0, 0);
            acc1 = __builtin_amdgcn_mfma_f32_32x32x16_bf16(zhA[j], elB1[j], acc1, 0, 0, 0);
        }
#pragma unroll
        for (int j = 0; j < 4; ++j) {
            acc0 = __builtin_amdgcn_mfma_f32_32x32x16_bf16(zlA[j], ehB0[j], acc0, 0, 0, 0);
            acc1 = __builtin_amdgcn_mfma_f32_32x32x16_bf16(zlA[j], ehB1[j], acc1, 0, 0, 0);
        }
        __builtin_amdgcn_s_setprio(0);

        if (ch < 7) {
            writeE(buf ^ 1);
            if (ch < 6) loadE(cb + 128);
        }

#pragma unroll
        for (int i = 0; i < 16; ++i) {
            float s0 = acc0[i];
            t2s[i] = __builtin_amdgcn_fmed3f(t1s[i], t2s[i], s0);
            bool lt0 = s0 < t1s[i];
            t1s[i] = fminf(t1s[i], s0);
            t1c[i] = lt0 ? c0 : t1c[i];
            float s1 = acc1[i];
            t2s[i] = __builtin_amdgcn_fmed3f(t1s[i], t2s[i], s1);
            bool lt1 = s1 < t1s[i];
            t1s[i] = fminf(t1s[i], s1);
            t1c[i] = lt1 ? c1 : t1c[i];
        }
        __syncthreads();
    }

#pragma unroll
    for (int i = 0; i < 16; ++i) {
        float v = t1s[i], w = t2s[i];
        int   c = (int)t1c[i];
#pragma unroll
        for (int m = 1; m < 32; m <<= 1) {
            float ov = __shfl_xor(v, m);
            int   oc = __shfl_xor(c, m);
            float ow = __shfl_xor(w, m);
            float mx = fmaxf(v, ov);
            w = fminf(fminf(w, ow), mx);
            bool take = (ov < v) || (ov == v && oc < c);
            v = take ? ov : v;
            c = take ? oc : c;
        }
        if ((lane & 31) == 0) {
            int row = (i & 3) + ((i >> 2) << 3) + (h << 2);
            int n = n0 + wave * 32 + row;
            ws_t1[split * NROWS + n] = v;
            ws_t2[split * NROWS + n] = w;
            ws_c [split * NROWS + n] = c;
        }
    }
}

// ---------------------------------------------------------------------------
// Kernel 1b: combine the two K-splits. grid 256 x 256.
// second-of-union = min(max(t1a,t1b), winner's t2). Exact.
// ---------------------------------------------------------------------------
__global__ __launch_bounds__(256) void vq_combine(
    const float* __restrict__ ws_t1, const float* __restrict__ ws_t2,
    const int* __restrict__ ws_c, float* __restrict__ out,
    unsigned* __restrict__ counts, unsigned* __restrict__ rcnt,
    int* __restrict__ rlist)
{
    const int n = blockIdx.x * 256 + threadIdx.x;
    float t1a = ws_t1[n],         t1b = ws_t1[NROWS + n];
    float t2a = ws_t2[n],         t2b = ws_t2[NROWS + n];
    int   ca  = ws_c[n],          cb  = ws_c[NROWS + n];
    bool tb = t1b < t1a;            // tie -> split0 (lower code) wins
    float v = tb ? t1b : t1a;
    int   c = tb ? cb  : ca;
    float second = fminf(fmaxf(t1a, t1b), tb ? t2b : t2a);
    out[O_IDX + n] = (float)c;
    atomicAdd(&counts[c], 1u);
    if (second - v < BAND) {
        unsigned p = atomicAdd(rcnt, 1u);
        rlist[p] = n;
    }
}

// ---------------------------------------------------------------------------
// Kernel 1-fallback: monolithic MFMA dist (proven, round-10). grid 512.
// ---------------------------------------------------------------------------
__global__ __launch_bounds__(256, 2) void vq_dist_mono(
    const float* __restrict__ z, const short* __restrict__ eh_g,
    const short* __restrict__ el_g, const float* __restrict__ esq_g,
    float* __restrict__ out, unsigned* __restrict__ counts,
    unsigned* __restrict__ rcnt, int* __restrict__ rlist)
{
    __shared__ __align__(16) short zh_lds[128 * 64];
    __shared__ __align__(16) short zl_lds[128 * 64];
    __shared__ __align__(16) short eh_lds[2][64 * 64];
    __shared__ __align__(16) short el_lds[2][64 * 64];
    __shared__ float esq_lds[1024];

    const int tid  = threadIdx.x;
    const int lane = tid & 63;
    const int wave = tid >> 6;
    const int col  = lane & 31;
    const int h    = lane >> 5;
    const int n0   = blockIdx.x * 128;
    const int b    = n0 >> 10;
    const int hw0  = n0 & 1023;

    for (int it = 0; it < 4; ++it) {
        int task = it * 256 + tid;
        int row  = task & 127;
        int kq   = task >> 7;
        const float* zp = z + (size_t)b * 65536 + (size_t)(kq * 8) * 1024 + hw0 + row;
        bfrag vh, vl;
#pragma unroll
        for (int m = 0; m < 8; ++m) {
            float t = -2.0f * zp[m * 1024];
            unsigned hh = bf16r(t);
            float rem = t - bf16f(hh);
            vh[m] = (short)hh;
            vl[m] = (short)bf16r(rem);
        }
        int unit = kq ^ (row & 7);
        *(bfrag*)&zh_lds[row * 64 + unit * 8] = vh;
        *(bfrag*)&zl_lds[row * 64 + unit * 8] = vl;
    }
    for (int it = 0; it < 4; ++it) {
        int t = it * 256 + tid;
        esq_lds[t] = esq_g[t];
    }

    bfrag pfh[2], pfl[2];
    auto loadE = [&](int cb) {
#pragma unroll
        for (int q = 0; q < 2; ++q) {
            int u = q * 256 + tid;
            int code = u >> 3, m = u & 7;
            pfh[q] = *(const bfrag*)&eh_g[(size_t)(cb + code) * 64 + m * 8];
            pfl[q] = *(const bfrag*)&el_g[(size_t)(cb + code) * 64 + m * 8];
        }
    };
    auto writeE = [&](int buf) {
#pragma unroll
        for (int q = 0; q < 2; ++q) {
            int u = q * 256 + tid;
            int code = u >> 3, m = u & 7;
            int unit = ((code >> 5) * 4 + (m >> 1)) * 64 +
                       ((((m & 1) << 5) | (code & 31)) ^ (m & 7));
            *(bfrag*)&eh_lds[buf][unit * 8] = pfh[q];
            *(bfrag*)&el_lds[buf][unit * 8] = pfl[q];
        }
    };

    loadE(0);
    writeE(0);
    loadE(64);
    __syncthreads();

    const int wrow = wave * 32 + col;
    bfrag zhA[4], zlA[4];
#pragma unroll
    for (int j = 0; j < 4; ++j) {
        int kq = j * 2 + h;
        int unit = kq ^ (wrow & 7);
        zhA[j] = *(const bfrag*)&zh_lds[wrow * 64 + unit * 8];
        zlA[j] = *(const bfrag*)&zl_lds[wrow * 64 + unit * 8];
    }

    float t1s[16], t2s[16];
    unsigned t1c[16];
#pragma unroll
    for (int i = 0; i < 16; ++i) { t1s[i] = INFINITY; t2s[i] = INFINITY; t1c[i] = 0; }

    for (int ch = 0; ch < 16; ++ch) {
        const int cb  = ch * 64;
        const int buf = ch & 1;

        bfrag ehB0[4], elB0[4], ehB1[4], elB1[4];
#pragma unroll
        for (int j = 0; j < 4; ++j) {
            int m = j * 2 + h;
            int sw = (((h << 5) | col) ^ (m & 7));
            ehB0[j] = *(const bfrag*)&eh_lds[buf][(j * 64 + sw) * 8];
            elB0[j] = *(const bfrag*)&el_lds[buf][(j * 64 + sw) * 8];
            ehB1[j] = *(const bfrag*)&eh_lds[buf][((4 + j) * 64 + sw) * 8];
            elB1[j] = *(const bfrag*)&el_lds[buf][((4 + j) * 64 + sw) * 8];
        }
        const float esq0 = esq_lds[cb + col];
        const float esq1 = esq_lds[cb + 32 + col];
        const unsigned c0 = cb + col;
        const unsigned c1 = cb + 32 + col;

        f32x16 acc0, acc1;
#pragma unroll
        for (int i = 0; i < 16; ++i) { acc0[i] = esq0; acc1[i] = esq1; }

        __builtin_amdgcn_s_setprio(1);
#pragma unroll
        for (int j = 0; j < 4; ++j) {
            acc0 = __builtin_amdgcn_mfma_f32_32x32x16_bf16(zhA[j], ehB0[j], acc0, 0, 0, 0);
            acc1 = __builtin_amdgcn_mfma_f32_32x32x16_bf16(zhA[j], ehB1[j], acc1, 0, 0, 0);
        }
#pragma unroll
        for (int j = 0; j < 4; ++j) {
            acc0 = __builtin_amdgcn_mfma_f32_32x32x16_bf16(zhA[j], elB0[j], acc0, 0, 0, 0);
            acc1 = __builtin_amdgcn_mfma_f32_32x32x16_bf16(zhA[j], elB1[j], acc1, 0, 0, 0);
        }
#pragma unroll
        for (int j = 0; j < 4; ++j) {
            acc0 = __builtin_amdgcn_mfma_f32_32x32x16_bf16(zlA[j], ehB0[j], acc0, 0, 0, 0);
            acc1 = __builtin_amdgcn_mfma_f32_32x32x16_bf16(zlA[j], ehB1[j], acc1, 0, 0, 0);
        }
        __builtin_amdgcn_s_setprio(0);

        if (ch < 15) {
            writeE(buf ^ 1);
            if (ch < 14) loadE(cb + 128);
        }

#pragma unroll
        for (int i = 0; i < 16; ++i) {
            float s0 = acc0[i];
            t2s[i] = __builtin_amdgcn_fmed3f(t1s[i], t2s[i], s0);
            bool lt0 = s0 < t1s[i];
            t1s[i] = fminf(t1s[i], s0);
            t1c[i] = lt0 ? c0 : t1c[i];
            float s1 = acc1[i];
            t2s[i] = __builtin_amdgcn_fmed3f(t1s[i], t2s[i], s1);
            bool lt1 = s1 < t1s[i];
            t1s[i] = fminf(t1s[i], s1);
            t1c[i] = lt1 ? c1 : t1c[i];
        }
        __syncthreads();
    }

#pragma unroll
    for (int i = 0; i < 16; ++i) {
        float v = t1s[i], w = t2s[i];
        int   c = (int)t1c[i];
#pragma unroll
        for (int m = 1; m < 32; m <<= 1) {
            float ov = __shfl_xor(v, m);
            int   oc = __shfl_xor(c, m);
            float ow = __shfl_xor(w, m);
            float mx = fmaxf(v, ov);
            w = fminf(fminf(w, ow), mx);
            bool take = (ov < v) || (ov == v && oc < c);
            v = take ? ov : v;
            c = take ? oc : c;
        }
        if ((lane & 31) == 0) {
            int row = (i & 3) + ((i >> 2) << 3) + (h << 2);
            int n = n0 + wave * 32 + row;
            out[O_IDX + n] = (float)c;
            atomicAdd(&counts[c], 1u);
            if (w - v < BAND) {
                unsigned p = atomicAdd(rcnt, 1u);
                rlist[p] = n;
            }
        }
    }
}

// ---------------------------------------------------------------------------
// Kernel 2: exact fp32 rescore of uncertified rows. grid 256 x 256.
// ---------------------------------------------------------------------------
__global__ __launch_bounds__(256) void vq_rescore(
    const float* __restrict__ z, const float* __restrict__ emb,
    const float* __restrict__ esq, const unsigned* __restrict__ rcnt,
    const int* __restrict__ rlist, float* __restrict__ out,
    unsigned* __restrict__ counts)
{
    __shared__ float zrow[64];
    __shared__ float rs[4];
    __shared__ int   rc[4];
    const int tid = threadIdx.x;
    const unsigned cnt = rcnt[0];

    for (unsigned i = blockIdx.x; i < cnt; i += gridDim.x) {
        const int n = rlist[i];
        const int b = n >> 10, hw = n & 1023;
        __syncthreads();
        if (tid < 64) zrow[tid] = z[(size_t)b * 65536 + (size_t)tid * 1024 + hw];
        __syncthreads();

        float best = INFINITY; int bc = 0;
        for (int rep = 0; rep < 4; ++rep) {
            int code = rep * 256 + tid;
            const float4* er = (const float4*)(emb + (size_t)code * 64);
            float a0 = 0.f, a1 = 0.f, a2 = 0.f, a3 = 0.f;
#pragma unroll
            for (int q = 0; q < 16; ++q) {
                float4 e = er[q];
                a0 = fmaf(zrow[q * 4 + 0], e.x, a0);
                a1 = fmaf(zrow[q * 4 + 1], e.y, a1);
                a2 = fmaf(zrow[q * 4 + 2], e.z, a2);
                a3 = fmaf(zrow[q * 4 + 3], e.w, a3);
            }
            float s = fmaf(-2.f, (a0 + a1) + (a2 + a3), esq[code]);
            if (s < best || (s == best && code < bc)) { best = s; bc = code; }
        }
        for (int m = 1; m < 64; m <<= 1) {
            float ov = __shfl_xor(best, m);
            int   oc = __shfl_xor(bc, m);
            bool take = (ov < best) || (ov == best && oc < bc);
            best = take ? ov : best;
            bc   = take ? oc : bc;
        }
        if ((tid & 63) == 0) { rs[tid >> 6] = best; rc[tid >> 6] = bc; }
        __syncthreads();
        if (tid == 0) {
            float fb = rs[0]; int fc = rc[0];
#pragma unroll
            for (int q = 1; q < 4; ++q) {
                bool take = (rs[q] < fb) || (rs[q] == fb && rc[q] < fc);
                fb = take ? rs[q] : fb;
                fc = take ? rc[q] : fc;
            }
            int old = (int)out[O_IDX + n];
            if (fc != old) {
                atomicAdd(&counts[old], (unsigned)-1);
                atomicAdd(&counts[fc], 1u);
                out[O_IDX + n] = (float)fc;
            }
        }
    }
}

// ---------------------------------------------------------------------------
// Scatter kernels: in-block LDS scan of counts (no separate scan dispatch),
// 2 threads/row, grid 512 x 256.
// ---------------------------------------------------------------------------
template <bool FUSED>
__global__ __launch_bounds__(256) void vq_scatter(
    const float* __restrict__ z, const float* __restrict__ emb,
    float* __restrict__ out, float* __restrict__ zf,
    const unsigned* __restrict__ counts, unsigned* __restrict__ cursor,
    float* __restrict__ lossa)
{
    __shared__ unsigned offs_lds[1024];
    __shared__ unsigned wt[4], wb[4];
    const int tid  = threadIdx.x;
    const int lane = tid & 63;
    const int wave = tid >> 6;

    // exclusive scan of counts into LDS
    unsigned c0 = counts[tid * 4 + 0], c1 = counts[tid * 4 + 1];
    unsigned c2 = counts[tid * 4 + 2], c3 = counts[tid * 4 + 3];
    unsigned tot = c0 + c1 + c2 + c3;
    unsigned v = tot;
#pragma unroll
    for (int off = 1; off < 64; off <<= 1) {
        unsigned t = __shfl_up(v, off);
        if (lane >= off) v += t;
    }
    if (lane == 63) wt[wave] = v;
    __syncthreads();
    if (tid == 0) {
        unsigned base = 0;
#pragma unroll
        for (int i = 0; i < 4; ++i) { wb[i] = base; base += wt[i]; }
    }
    __syncthreads();
    unsigned ex = wb[wave] + (v - tot);
    offs_lds[tid * 4 + 0] = ex;
    offs_lds[tid * 4 + 1] = ex + c0;
    offs_lds[tid * 4 + 2] = ex + c0 + c1;
    offs_lds[tid * 4 + 3] = ex + c0 + c1 + c2;
    __syncthreads();

    const int gt = blockIdx.x * 256 + tid;
    const int n  = gt >> 1;
    const int h  = gt & 1;
    const int b  = n >> 10, hw = n & 1023;
    const int k  = (int)out[O_IDX + n];
    unsigned pos = 0;
    if (h == 0) pos = offs_lds[k] + atomicAdd(&cursor[k], 1u);
    pos = __shfl(pos, lane & 62);

    const float*  zb  = z + (size_t)b * 65536 + (size_t)h * 32768 + hw;
    const float4* ek4 = (const float4*)emb + (size_t)k * 16 + h * 8;
    float* dst = (FUSED ? zf : out + O_ZQ) + (size_t)pos * 64 + h * 32;
    float* oq  = out + O_ZQ + (size_t)b * 65536 + (size_t)h * 32768 + hw;

    float lacc = 0.f;
#pragma unroll
    for (int i = 0; i < 8; ++i) {
        float4 e = ek4[i];
        float z0 = zb[(i * 4 + 0) * 1024];
        float z1 = zb[(i * 4 + 1) * 1024];
        float z2 = zb[(i * 4 + 2) * 1024];
        float z3 = zb[(i * 4 + 3) * 1024];
        *(float4*)&dst[i * 4] = make_float4(z0, z1, z2, z3);
        if (FUSED) {
            oq[(i * 4 + 0) * 1024] = z0 + (e.x - z0);
            oq[(i * 4 + 1) * 1024] = z1 + (e.y - z1);
            oq[(i * 4 + 2) * 1024] = z2 + (e.z - z2);
            oq[(i * 4 + 3) * 1024] = z3 + (e.w - z3);
        }
        float d0 = z0 - e.x, d1 = z1 - e.y, d2 = z2 - e.z, d3 = z3 - e.w;
        lacc = fmaf(d0, d0, lacc);
        lacc = fmaf(d1, d1, lacc);
        lacc = fmaf(d2, d2, lacc);
        lacc = fmaf(d3, d3, lacc);
    }

    for (int off = 32; off; off >>= 1) lacc += __shfl_down(lacc, off);
    if ((tid & 63) == 0) atomicAdd(lossa, lacc);
}

// ---------------------------------------------------------------------------
// Kernel 5: dw + EMA update. In-block offs[k] + n recompute (no scan kernel).
// grid 1024 x 256.
// ---------------------------------------------------------------------------
__global__ __launch_bounds__(256) void vq_upd_kernel(
    const float* __restrict__ zsrc, const unsigned* __restrict__ counts,
    const float* __restrict__ cs, const float* __restrict__ ema_w,
    const float* __restrict__ lossa, float* __restrict__ out)
{
    __shared__ float    red[4][64];
    __shared__ float    nr[4];
    __shared__ unsigned orr[4];
    const int k    = blockIdx.x;
    const int tid  = threadIdx.x;
    const int lane = tid & 63;
    const int wave = tid >> 6;
    const int d    = tid & 63;
    const int q    = tid >> 6;

    // offs[k] = sum counts[j<k]; n = sum ncs
    float    npart = 0.f;
    unsigned opart = 0;
#pragma unroll
    for (int it = 0; it < 4; ++it) {
        int j = it * 256 + tid;
        unsigned cj = counts[j];
        npart += 0.99f * cs[j] + 0.01f * (float)cj;
        if (j < k) opart += cj;
    }
#pragma unroll
    for (int off = 32; off; off >>= 1) {
        npart += __shfl_down(npart, off);
        opart += __shfl_down(opart, off);
    }
    if (lane == 0) { nr[wave] = npart; orr[wave] = opart; }
    __syncthreads();
    const float    n   = (nr[0] + nr[1]) + (nr[2] + nr[3]);
    const unsigned off = orr[0] + orr[1] + orr[2] + orr[3];
    const unsigned cnt = counts[k];

    float acc = 0.f;
    unsigned j = q;
    for (; j + 12 < cnt; j += 16) {
        acc += zsrc[(size_t)(off + j)      * 64 + d];
        acc += zsrc[(size_t)(off + j + 4)  * 64 + d];
        acc += zsrc[(size_t)(off + j + 8)  * 64 + d];
        acc += zsrc[(size_t)(off + j + 12) * 64 + d];
    }
    for (; j < cnt; j += 4) acc += zsrc[(size_t)(off + j) * 64 + d];

    red[q][d] = acc;
    __syncthreads();
    if (q == 0) {
        float dw = red[0][d] + red[1][d] + red[2][d] + red[3][d];
        float nw = 0.99f * ema_w[k * 64 + d] + 0.01f * dw;
        out[O_EMAW + k * 64 + d] = nw;
        float ncs = 0.99f * cs[k] + 0.01f * (float)cnt;
        float csv = (ncs + 1e-5f) / (n + 1024e-5f) * n;
        out[O_EMB + k * 64 + d] = nw / csv;
        if (d == 0) out[O_NCS + k] = ncs;
    }
    if (k == 0 && tid == 0)
        out[O_LOSS] = 0.25f * lossa[0] / (float)NELEM;
}

// ---------------------------------------------------------------------------
// Kernel 6 (sep path only): final z_q_st writer. grid 512 x 256.
// ---------------------------------------------------------------------------
__global__ __launch_bounds__(256) void vq_zqwrite_kernel(
    const float* __restrict__ z, const float* __restrict__ emb,
    float* __restrict__ out)
{
    const int tid = threadIdx.x;
    const int n   = blockIdx.x * 128 + (tid & 127);
    const int h   = tid >> 7;
    const int b   = n >> 10;
    const int hw  = n & 1023;
    const int k   = (int)out[O_IDX + n];

    const float*  zb  = z   + (size_t)b * 65536 + (size_t)h * 32768 + hw;
    float*        oq  = out + O_ZQ + (size_t)b * 65536 + (size_t)h * 32768 + hw;
    const float4* ek4 = (const float4*)emb + (size_t)k * 16 + h * 8;

#pragma unroll
    for (int i = 0; i < 8; ++i) {
        float4 e = ek4[i];
        float z0 = zb[(i * 4 + 0) * 1024];
        float z1 = zb[(i * 4 + 1) * 1024];
        float z2 = zb[(i * 4 + 2) * 1024];
        float z3 = zb[(i * 4 + 3) * 1024];
        oq[(i * 4 + 0) * 1024] = z0 + (e.x - z0);
        oq[(i * 4 + 1) * 1024] = z1 + (e.y - z1);
        oq[(i * 4 + 2) * 1024] = z2 + (e.z - z2);
        oq[(i * 4 + 3) * 1024] = z3 + (e.w - z3);
    }
}

// ---------------------------------------------------------------------------
extern "C" void kernel_launch(void* const* d_in, const int* in_sizes, int n_in,
                              void* d_out, int out_size, void* d_ws, size_t ws_size,
                              hipStream_t stream) {
    const float* z     = (const float*)d_in[0];
    const float* emb   = (const float*)d_in[1];
    const float* cs    = (const float*)d_in[2];
    const float* ema_w = (const float*)d_in[3];
    float* out = (float*)d_out;

    char* W = (char*)d_ws;
    short*    eh_g   = (short*)(W + WB_EH);
    short*    el_g   = (short*)(W + WB_EL);
    float*    esq    = (float*)(W + WB_ESQ);
    unsigned* counts = (unsigned*)(W + WB_COUNTS);
    unsigned* cursor = (unsigned*)(W + WB_CURSOR);
    float*    lossa  = (float*)(W + WB_LOSSN);
    unsigned* rcnt   = (unsigned*)(W + WB_LOSSN + 0x100);
    int*      rlist  = (int*)(W + WB_RLIST);
    float*    ws_t1  = (float*)(W + WB_T1);
    float*    ws_t2  = (float*)(W + WB_T2);
    int*      ws_c   = (int*)(W + WB_C);
    float*    zf     = (float*)(W + WB_ZF);

    const bool split = ws_size >= (size_t)WS_NEED_SPLIT;
    const bool fused = ws_size >= (size_t)WS_NEED_FUSED;

    vq_prep_e<<<256, 256, 0, stream>>>(emb, (ushort*)eh_g, (ushort*)el_g, esq,
                                       counts);
    if (split) {
        vq_dist_split<<<1024, 256, 0, stream>>>(z, eh_g, el_g, esq,
                                                ws_t1, ws_t2, ws_c);
        vq_combine<<<256, 256, 0, stream>>>(ws_t1, ws_t2, ws_c, out, counts,
                                            rcnt, rlist);
    } else {
        vq_dist_mono<<<512, 256, 0, stream>>>(z, eh_g, el_g, esq, out, counts,
                                              rcnt, rlist);
    }
    vq_rescore<<<256, 256, 0, stream>>>(z, emb, esq, rcnt, rlist, out, counts);
    if (fused) {
        vq_scatter<true><<<512, 256, 0, stream>>>(z, emb, out, zf, counts,
                                                  cursor, lossa);
        vq_upd_kernel<<<1024, 256, 0, stream>>>(zf, counts, cs, ema_w, lossa,
                                                out);
    } else {
        vq_scatter<false><<<512, 256, 0, stream>>>(z, emb, out, zf, counts,
                                                   cursor, lossa);
        vq_upd_kernel<<<1024, 256, 0, stream>>>(out + O_ZQ, counts, cs, ema_w,
                                                lossa, out);
        vq_zqwrite_kernel<<<512, 256, 0, stream>>>(z, emb, out);
    }
}